// Round 1
// baseline (10010.249 us; speedup 1.0000x reference)
//
#include <hip/hip_runtime.h>
#include <hip/hip_bf16.h>

// Problem constants (match reference)
constexpr int B  = 2;
constexpr int S  = 2048;
constexpr int D  = 2048;
constexpr int H  = 32;
constexpr int G  = 8;
constexpr int HD = 64;
constexpr float EPS = 1e-6f;

// ---------------------------------------------------------------------------
// GEMM: C[M][N] = A[M][K] @ B[N][K]^T   (both row-major, K contiguous: "NT")
// 64x64 tile, BK=16, 256 threads, 4x4 micro-tile per thread.
// ---------------------------------------------------------------------------
__global__ __launch_bounds__(256) void gemm_nt(const float* __restrict__ A,
                                               const float* __restrict__ Bm,
                                               float* __restrict__ C,
                                               int M, int N, int K)
{
    constexpr int BM = 64, BN = 64, BK = 16;
    __shared__ float As[BK][BM];
    __shared__ float Bs[BK][BN];

    const int tid = threadIdx.x;
    const int tx  = tid & 15;        // 16 thread-cols
    const int ty  = tid >> 4;        // 16 thread-rows
    const int bm  = blockIdx.y * BM;
    const int bn  = blockIdx.x * BN;

    // cooperative loader mapping: 256 threads x float4 = 1024 floats = one tile
    const int lrow = tid >> 2;          // 0..63
    const int lk   = (tid & 3) * 4;     // 0,4,8,12

    float acc[4][4] = {};

    for (int k0 = 0; k0 < K; k0 += BK) {
        float4 av = *(const float4*)(A  + (size_t)(bm + lrow) * K + k0 + lk);
        float4 bv = *(const float4*)(Bm + (size_t)(bn + lrow) * K + k0 + lk);
        As[lk + 0][lrow] = av.x; As[lk + 1][lrow] = av.y;
        As[lk + 2][lrow] = av.z; As[lk + 3][lrow] = av.w;
        Bs[lk + 0][lrow] = bv.x; Bs[lk + 1][lrow] = bv.y;
        Bs[lk + 2][lrow] = bv.z; Bs[lk + 3][lrow] = bv.w;
        __syncthreads();

        #pragma unroll
        for (int k = 0; k < BK; ++k) {
            float4 a4 = *(const float4*)&As[k][ty * 4];
            float4 b4 = *(const float4*)&Bs[k][tx * 4];
            float ar[4] = {a4.x, a4.y, a4.z, a4.w};
            float br[4] = {b4.x, b4.y, b4.z, b4.w};
            #pragma unroll
            for (int i = 0; i < 4; ++i)
                #pragma unroll
                for (int j = 0; j < 4; ++j)
                    acc[i][j] = fmaf(ar[i], br[j], acc[i][j]);
        }
        __syncthreads();
    }

    #pragma unroll
    for (int i = 0; i < 4; ++i)
        #pragma unroll
        for (int j = 0; j < 4; ++j)
            C[(size_t)(bm + ty * 4 + i) * N + (bn + tx * 4 + j)] = acc[i][j];
}

// ---------------------------------------------------------------------------
// Fused RMSNorm + RoPE + (optional) scale, in place.
// t layout: (B*S rows) x (heads*HD), one wave per (row, head).
// ---------------------------------------------------------------------------
__global__ __launch_bounds__(64) void norm_rope(float* __restrict__ t,
                                                const float* __restrict__ cosb,
                                                const float* __restrict__ sinb,
                                                const float* __restrict__ scale,
                                                int heads, float mulscale)
{
    const int lane = threadIdx.x;             // head-dim element, 0..63
    const int idx  = blockIdx.x;
    const int h    = idx % heads;
    const int m    = idx / heads;             // row in [0, B*S)
    const int s    = m % S;                   // sequence position

    float* row = t + (size_t)m * heads * HD + h * HD;
    float v = row[lane];

    float sq = v * v;
    #pragma unroll
    for (int off = 32; off; off >>= 1) sq += __shfl_xor(sq, off, 64);
    float inv = rsqrtf(sq * (1.0f / HD) + EPS);
    float n = v * inv * (1.0f + scale[lane]);

    // RoPE: rotated = concat(-t2, t1)
    float other = __shfl_xor(n, 32, 64);
    float rot   = (lane < 32) ? -other : other;
    float c  = cosb[(size_t)s * HD + lane];
    float sn = sinb[(size_t)s * HD + lane];
    row[lane] = (n * c + rot * sn) * mulscale;
}

// ---------------------------------------------------------------------------
// Causal GQA attention, one wave per (b, h, qpos). lane = head-dim element.
// Online softmax over keys 0..qpos. K/V total 16.8 MB -> LLC-resident.
// ---------------------------------------------------------------------------
__global__ __launch_bounds__(64) void attn(const float* __restrict__ qb,
                                           const float* __restrict__ kb,
                                           const float* __restrict__ vb,
                                           float* __restrict__ ctx)
{
    const int lane = threadIdx.x;
    const int idx  = blockIdx.x;
    const int qp   = idx % S;                 // fastest: consecutive blocks share K/V
    const int h    = (idx / S) % H;
    const int b    = idx / (S * H);
    const int g    = h / (H / G);

    const float qv = qb[((size_t)(b * S + qp) * H + h) * HD + lane];
    const float* kbase = kb + ((size_t)b * S * G + g) * HD;
    const float* vbase = vb + ((size_t)b * S * G + g) * HD;

    float m = -INFINITY, l = 0.f, acc = 0.f;
    for (int j = 0; j <= qp; ++j) {
        float kvv = kbase[(size_t)j * G * HD + lane];
        float p = qv * kvv;
        #pragma unroll
        for (int off = 32; off; off >>= 1) p += __shfl_xor(p, off, 64);
        float mn   = fmaxf(m, p);
        float corr = __expf(m - mn);
        float w    = __expf(p - mn);
        float vvv  = vbase[(size_t)j * G * HD + lane];
        acc = acc * corr + w * vvv;
        l   = l   * corr + w;
        m   = mn;
    }
    ctx[((size_t)(b * S + qp) * H + h) * HD + lane] = acc / l;
}

// ---------------------------------------------------------------------------
extern "C" void kernel_launch(void* const* d_in, const int* in_sizes, int n_in,
                              void* d_out, int out_size, void* d_ws, size_t ws_size,
                              hipStream_t stream)
{
    const float* x       = (const float*)d_in[0];
    // d_in[1] = mask (bool) — ignored; causality computed structurally (k > q)
    const float* cosb    = (const float*)d_in[2];
    const float* sinb    = (const float*)d_in[3];
    const float* Wq      = (const float*)d_in[4];
    const float* Wk      = (const float*)d_in[5];
    const float* Wv      = (const float*)d_in[6];
    const float* Wo      = (const float*)d_in[7];
    const float* q_scale = (const float*)d_in[8];
    const float* k_scale = (const float*)d_in[9];
    float* out = (float*)d_out;

    // workspace layout (floats)
    float* ws  = (float*)d_ws;
    float* q   = ws;                              // B*S*H*HD  = 8388608
    float* k   = q + (size_t)B * S * H * HD;      // B*S*G*HD  = 2097152
    float* v   = k + (size_t)B * S * G * HD;      // 2097152
    float* ctx = v + (size_t)B * S * G * HD;      // 8388608

    const int M = B * S;          // 4096
    dim3 blk(256);

    // q = x @ Wq^T   (M x 2048)
    gemm_nt<<<dim3((H * HD) / 64, M / 64), blk, 0, stream>>>(x, Wq, q, M, H * HD, D);
    // k = x @ Wk^T   (M x 512)
    gemm_nt<<<dim3((G * HD) / 64, M / 64), blk, 0, stream>>>(x, Wk, k, M, G * HD, D);
    // v = x @ Wv^T
    gemm_nt<<<dim3((G * HD) / 64, M / 64), blk, 0, stream>>>(x, Wv, v, M, G * HD, D);

    // RMSNorm + RoPE (+ q scaled by HD^-0.5)
    norm_rope<<<M * H, 64, 0, stream>>>(q, cosb, sinb, q_scale, H, 0.125f);
    norm_rope<<<M * G, 64, 0, stream>>>(k, cosb, sinb, k_scale, G, 1.0f);

    // attention -> ctx in (b, s, h*HD) layout
    attn<<<B * H * S, 64, 0, stream>>>(q, k, v, ctx);

    // out = ctx @ Wo^T   (M x 2048)
    gemm_nt<<<dim3(D / 64, M / 64), blk, 0, stream>>>(ctx, Wo, out, M, D, D);
}

// Round 3
// 3393.428 us; speedup vs baseline: 2.9499x; 2.9499x over previous
//
#include <hip/hip_runtime.h>
#include <hip/hip_bf16.h>
#include <stdint.h>

// Problem constants (match reference)
constexpr int B  = 2;
constexpr int S  = 2048;
constexpr int D  = 2048;
constexpr int H  = 32;
constexpr int G  = 8;
constexpr int HD = 64;
constexpr float EPS = 1e-6f;

// ---------------------------------------------------------------------------
// GEMM: C[M][N] = A[M][K] @ B[N][K]^T   (both row-major, K contiguous: "NT")
// 64x64 tile, BK=16, 256 threads, 4x4 micro-tile per thread.
// ---------------------------------------------------------------------------
__global__ __launch_bounds__(256) void gemm_nt(const float* __restrict__ A,
                                               const float* __restrict__ Bm,
                                               float* __restrict__ C,
                                               int M, int N, int K)
{
    constexpr int BM = 64, BN = 64, BK = 16;
    __shared__ float As[BK][BM];
    __shared__ float Bs[BK][BN];

    const int tid = threadIdx.x;
    const int tx  = tid & 15;
    const int ty  = tid >> 4;
    const int bm  = blockIdx.y * BM;
    const int bn  = blockIdx.x * BN;

    const int lrow = tid >> 2;
    const int lk   = (tid & 3) * 4;

    float acc[4][4] = {};

    for (int k0 = 0; k0 < K; k0 += BK) {
        float4 av = *(const float4*)(A  + (size_t)(bm + lrow) * K + k0 + lk);
        float4 bv = *(const float4*)(Bm + (size_t)(bn + lrow) * K + k0 + lk);
        As[lk + 0][lrow] = av.x; As[lk + 1][lrow] = av.y;
        As[lk + 2][lrow] = av.z; As[lk + 3][lrow] = av.w;
        Bs[lk + 0][lrow] = bv.x; Bs[lk + 1][lrow] = bv.y;
        Bs[lk + 2][lrow] = bv.z; Bs[lk + 3][lrow] = bv.w;
        __syncthreads();

        #pragma unroll
        for (int k = 0; k < BK; ++k) {
            float4 a4 = *(const float4*)&As[k][ty * 4];
            float4 b4 = *(const float4*)&Bs[k][tx * 4];
            float ar[4] = {a4.x, a4.y, a4.z, a4.w};
            float br[4] = {b4.x, b4.y, b4.z, b4.w};
            #pragma unroll
            for (int i = 0; i < 4; ++i)
                #pragma unroll
                for (int j = 0; j < 4; ++j)
                    acc[i][j] = fmaf(ar[i], br[j], acc[i][j]);
        }
        __syncthreads();
    }

    #pragma unroll
    for (int i = 0; i < 4; ++i)
        #pragma unroll
        for (int j = 0; j < 4; ++j)
            C[(size_t)(bm + ty * 4 + i) * N + (bn + tx * 4 + j)] = acc[i][j];
}

// ---------------------------------------------------------------------------
// Fused RMSNorm + RoPE + (optional) scale, in place.
// ---------------------------------------------------------------------------
__global__ __launch_bounds__(64) void norm_rope(float* __restrict__ t,
                                                const float* __restrict__ cosb,
                                                const float* __restrict__ sinb,
                                                const float* __restrict__ scale,
                                                int heads, float mulscale)
{
    const int lane = threadIdx.x;
    const int idx  = blockIdx.x;
    const int h    = idx % heads;
    const int m    = idx / heads;
    const int s    = m % S;

    float* row = t + (size_t)m * heads * HD + h * HD;
    float v = row[lane];

    float sq = v * v;
    #pragma unroll
    for (int off = 32; off; off >>= 1) sq += __shfl_xor(sq, off, 64);
    float inv = rsqrtf(sq * (1.0f / HD) + EPS);
    float n = v * inv * (1.0f + scale[lane]);

    float other = __shfl_xor(n, 32, 64);
    float rot   = (lane < 32) ? -other : other;
    float c  = cosb[(size_t)s * HD + lane];
    float sn = sinb[(size_t)s * HD + lane];
    row[lane] = (n * c + rot * sn) * mulscale;
}

// ---------------------------------------------------------------------------
// Flash attention, thread = query. One wave (64 threads) handles q-tile qt
// AND its mirror (31-qt) sequentially -> uniform 66 key-tiles per wave.
// K/V tiles (32 keys x 64 dims fp32) double-buffered in LDS via
// global_load_lds; all compute-phase LDS reads are wave-uniform broadcasts.
// ---------------------------------------------------------------------------
typedef __attribute__((address_space(1))) const uint32_t  gas_u32;
typedef __attribute__((address_space(3))) uint32_t        las_u32;

__global__ __launch_bounds__(64) void attn_flash(const float* __restrict__ qb,
                                                 const float* __restrict__ kb,
                                                 const float* __restrict__ vb,
                                                 float* __restrict__ ctx)
{
    constexpr int KT  = 32;           // keys per tile
    constexpr int NQT = S / 64;       // 32 q-tiles per (b,h)

    __shared__ float Klds[2][KT * HD];
    __shared__ float Vlds[2][KT * HD];

    const int lane = threadIdx.x;
    const int blk  = blockIdx.x;
    const int qt0  = blk & 15;            // pair index (qt0, 31-qt0)
    const int bh   = blk >> 4;
    const int h    = bh & (H - 1);
    const int b    = bh >> 5;
    const int g    = h >> 2;              // H/G = 4

    const float* kbase = kb + ((size_t)b * S * G + g) * HD;
    const float* vbase = vb + ((size_t)b * S * G + g) * HD;

    // stage tile t (keys t*32..t*32+31) into buffer buf
    auto stage = [&](int t, int buf) {
        const int j0 = t * KT;
        #pragma unroll
        for (int r = 0; r < 8; ++r) {
            const int f   = r * 64 + lane;     // float4 index in tile (0..511)
            const int row = f >> 4;
            const int c4  = f & 15;
            const float* ksrc = kbase + (size_t)(j0 + row) * (G * HD) + c4 * 4;
            const float* vsrc = vbase + (size_t)(j0 + row) * (G * HD) + c4 * 4;
            __builtin_amdgcn_global_load_lds((gas_u32*)ksrc,
                                             (las_u32*)&Klds[buf][r * 256], 16, 0, 0);
            __builtin_amdgcn_global_load_lds((gas_u32*)vsrc,
                                             (las_u32*)&Vlds[buf][r * 256], 16, 0, 0);
        }
    };

    for (int pass = 0; pass < 2; ++pass) {
        const int qt    = pass ? (NQT - 1 - qt0) : qt0;
        const int qp    = qt * 64 + lane;
        const int nt    = 2 * qt + 2;       // key-tiles covering 0..qt*64+63

        // own q row -> registers
        float4 q[16];
        const float4* qrow = (const float4*)(qb + ((size_t)(b * S + qp) * H + h) * HD);
        #pragma unroll
        for (int i = 0; i < 16; ++i) q[i] = qrow[i];

        float4 acc[16];
        #pragma unroll
        for (int i = 0; i < 16; ++i) acc[i] = make_float4(0.f, 0.f, 0.f, 0.f);
        float m = -INFINITY, l = 0.f;

        stage(0, 0);

        for (int t = 0; t < nt; ++t) {
            const int cur = t & 1;
            const int j0  = t * KT;
            if (t + 1 < nt) {
                stage(t + 1, cur ^ 1);
                asm volatile("s_waitcnt vmcnt(16)" ::: "memory");
            } else {
                asm volatile("s_waitcnt vmcnt(0)" ::: "memory");
            }

            // ---- scores for 32 keys (uniform broadcast LDS reads) ----
            float sc[KT];
            const float4* kt = (const float4*)&Klds[cur][0];
            #pragma unroll
            for (int j = 0; j < KT; ++j) {
                float s0 = 0.f, s1 = 0.f, s2 = 0.f, s3 = 0.f;
                #pragma unroll
                for (int d = 0; d < 16; ++d) {
                    float4 kv = kt[j * 16 + d];
                    s0 = fmaf(q[d].x, kv.x, s0);
                    s1 = fmaf(q[d].y, kv.y, s1);
                    s2 = fmaf(q[d].z, kv.z, s2);
                    s3 = fmaf(q[d].w, kv.w, s3);
                }
                sc[j] = (j0 + j <= qp) ? ((s0 + s1) + (s2 + s3)) : -INFINITY;
            }

            // ---- online softmax: one deferred rescale per tile ----
            float mt = sc[0];
            #pragma unroll
            for (int j = 1; j < KT; ++j) mt = fmaxf(mt, sc[j]);
            const float mn   = fmaxf(m, mt);
            const float corr = __expf(m - mn);
            l *= corr;
            #pragma unroll
            for (int d = 0; d < 16; ++d) {
                acc[d].x *= corr; acc[d].y *= corr;
                acc[d].z *= corr; acc[d].w *= corr;
            }

            const float4* vt = (const float4*)&Vlds[cur][0];
            #pragma unroll
            for (int j = 0; j < KT; ++j) {
                const float w = __expf(sc[j] - mn);
                l += w;
                #pragma unroll
                for (int d = 0; d < 16; ++d) {
                    float4 vv = vt[j * 16 + d];
                    acc[d].x = fmaf(w, vv.x, acc[d].x);
                    acc[d].y = fmaf(w, vv.y, acc[d].y);
                    acc[d].z = fmaf(w, vv.z, acc[d].z);
                    acc[d].w = fmaf(w, vv.w, acc[d].w);
                }
            }
            m = mn;
        }

        const float inv = 1.f / l;
        float4* crow = (float4*)(ctx + ((size_t)(b * S + qp) * H + h) * HD);
        #pragma unroll
        for (int d = 0; d < 16; ++d) {
            float4 o = acc[d];
            o.x *= inv; o.y *= inv; o.z *= inv; o.w *= inv;
            crow[d] = o;
        }
    }
}

// ---------------------------------------------------------------------------
extern "C" void kernel_launch(void* const* d_in, const int* in_sizes, int n_in,
                              void* d_out, int out_size, void* d_ws, size_t ws_size,
                              hipStream_t stream)
{
    const float* x       = (const float*)d_in[0];
    // d_in[1] = mask (bool) — ignored; causality computed structurally (k > q)
    const float* cosb    = (const float*)d_in[2];
    const float* sinb    = (const float*)d_in[3];
    const float* Wq      = (const float*)d_in[4];
    const float* Wk      = (const float*)d_in[5];
    const float* Wv      = (const float*)d_in[6];
    const float* Wo      = (const float*)d_in[7];
    const float* q_scale = (const float*)d_in[8];
    const float* k_scale = (const float*)d_in[9];
    float* out = (float*)d_out;

    float* ws  = (float*)d_ws;
    float* q   = ws;                              // B*S*H*HD
    float* k   = q + (size_t)B * S * H * HD;      // B*S*G*HD
    float* v   = k + (size_t)B * S * G * HD;
    float* ctx = v + (size_t)B * S * G * HD;      // B*S*H*HD

    const int M = B * S;          // 4096
    dim3 blk(256);

    gemm_nt<<<dim3((H * HD) / 64, M / 64), blk, 0, stream>>>(x, Wq, q, M, H * HD, D);
    gemm_nt<<<dim3((G * HD) / 64, M / 64), blk, 0, stream>>>(x, Wk, k, M, G * HD, D);
    gemm_nt<<<dim3((G * HD) / 64, M / 64), blk, 0, stream>>>(x, Wv, v, M, G * HD, D);

    norm_rope<<<M * H, 64, 0, stream>>>(q, cosb, sinb, q_scale, H, 0.125f);
    norm_rope<<<M * G, 64, 0, stream>>>(k, cosb, sinb, k_scale, G, 1.0f);

    // flash attention: 16 q-tile pairs x 64 (b,h) = 1024 one-wave blocks
    attn_flash<<<16 * B * H, 64, 0, stream>>>(q, k, v, ctx);

    gemm_nt<<<dim3(D / 64, M / 64), blk, 0, stream>>>(ctx, Wo, out, M, D, D);
}

// Round 5
// 1570.707 us; speedup vs baseline: 6.3731x; 2.1604x over previous
//
#include <hip/hip_runtime.h>
#include <hip/hip_bf16.h>
#include <stdint.h>

// Problem constants (match reference)
constexpr int B  = 2;
constexpr int S  = 2048;
constexpr int D  = 2048;
constexpr int H  = 32;
constexpr int G  = 8;
constexpr int HD = 64;
constexpr float EPS = 1e-6f;

typedef __attribute__((address_space(1))) const uint32_t  gas_u32;
typedef __attribute__((address_space(3))) uint32_t        las_u32;
typedef __attribute__((ext_vector_type(8))) short  bf16x8;   // 8 bf16 = 4 VGPR
typedef __attribute__((ext_vector_type(4))) float  f32x4;

static __device__ __forceinline__ unsigned short f2b(float f) {
    __hip_bfloat16 h = __float2bfloat16(f);
    return *reinterpret_cast<unsigned short*>(&h);
}

// ---------------------------------------------------------------------------
// f32 -> bf16 elementwise conversion (vectorized, grid-stride)
// ---------------------------------------------------------------------------
__global__ __launch_bounds__(256) void conv_f2b(const float* __restrict__ in,
                                                unsigned short* __restrict__ out,
                                                int n4)
{
    int i = blockIdx.x * blockDim.x + threadIdx.x;
    const int stride = gridDim.x * blockDim.x;
    for (; i < n4; i += stride) {
        float4 v = ((const float4*)in)[i];
        ushort4 o;
        o.x = f2b(v.x); o.y = f2b(v.y); o.z = f2b(v.z); o.w = f2b(v.w);
        ((ushort4*)out)[i] = o;
    }
}

// ---------------------------------------------------------------------------
// bf16 MFMA GEMM: C[M][N] = A[M][K] @ B[N][K]^T, A/B bf16 (as ushort), C f32.
// 128x128 tile, BK=64, 256 threads = 4 waves (2x2), 16x16x32 MFMA.
// global_load_lds width-16 staging with XOR chunk swizzle (involution on
// both write-source and read side, rule #21). M,N % 128 == 0, K % 64 == 0.
// ---------------------------------------------------------------------------
__global__ __launch_bounds__(256) void gemm_bf16(const unsigned short* __restrict__ A,
                                                 const unsigned short* __restrict__ Bm,
                                                 float* __restrict__ C,
                                                 int M, int N, int K)
{
    constexpr int BM = 128, BN = 128, BK = 64;
    __shared__ unsigned short As[BM * BK];   // 16 KB, [r][slot] 16B chunks
    __shared__ unsigned short Bs[BN * BK];   // 16 KB

    const int tid  = threadIdx.x;
    const int w    = tid >> 6;
    const int lane = tid & 63;
    const int wr   = w >> 1, wc = w & 1;     // 2x2 wave grid
    const int bm   = blockIdx.y * BM;
    const int bn   = blockIdx.x * BN;

    f32x4 acc[4][4];
    #pragma unroll
    for (int mi = 0; mi < 4; ++mi)
        #pragma unroll
        for (int ni = 0; ni < 4; ++ni)
            acc[mi][ni] = (f32x4){0.f, 0.f, 0.f, 0.f};

    for (int k0 = 0; k0 < K; k0 += BK) {
        // stage A: 1024 chunks of 16B; 4 per thread. LDS slot cs holds global
        // chunk cs ^ (r&7)  (bank-conflict swizzle).
        #pragma unroll
        for (int i = 0; i < 4; ++i) {
            const int n  = i * 256 + tid;
            const int r  = n >> 3, cs = n & 7;
            const int cg = cs ^ (r & 7);
            const unsigned short* ga = A + (size_t)(bm + r) * K + k0 + cg * 8;
            __builtin_amdgcn_global_load_lds((gas_u32*)ga,
                (las_u32*)(As + (i * 256 + w * 64) * 8), 16, 0, 0);
        }
        #pragma unroll
        for (int i = 0; i < 4; ++i) {
            const int n  = i * 256 + tid;
            const int r  = n >> 3, cs = n & 7;
            const int cg = cs ^ (r & 7);
            const unsigned short* gb = Bm + (size_t)(bn + r) * K + k0 + cg * 8;
            __builtin_amdgcn_global_load_lds((gas_u32*)gb,
                (las_u32*)(Bs + (i * 256 + w * 64) * 8), 16, 0, 0);
        }
        asm volatile("s_waitcnt vmcnt(0)" ::: "memory");
        __syncthreads();

        #pragma unroll
        for (int ks = 0; ks < 2; ++ks) {
            bf16x8 af[4], bfr[4];
            #pragma unroll
            for (int mi = 0; mi < 4; ++mi) {
                const int r    = wr * 64 + mi * 16 + (lane & 15);
                const int c    = ks * 4 + (lane >> 4);
                const int slot = c ^ (r & 7);
                af[mi] = *(const bf16x8*)(As + r * 64 + slot * 8);
            }
            #pragma unroll
            for (int ni = 0; ni < 4; ++ni) {
                const int r    = wc * 64 + ni * 16 + (lane & 15);
                const int c    = ks * 4 + (lane >> 4);
                const int slot = c ^ (r & 7);
                bfr[ni] = *(const bf16x8*)(Bs + r * 64 + slot * 8);
            }
            #pragma unroll
            for (int mi = 0; mi < 4; ++mi)
                #pragma unroll
                for (int ni = 0; ni < 4; ++ni)
                    acc[mi][ni] = __builtin_amdgcn_mfma_f32_16x16x32_bf16(
                        af[mi], bfr[ni], acc[mi][ni], 0, 0, 0);
        }
        __syncthreads();
    }

    // epilogue: C/D layout col = lane&15, row = (lane>>4)*4 + reg
    const int col0 = bn + wc * 64 + (lane & 15);
    const int row0 = bm + wr * 64 + (lane >> 4) * 4;
    #pragma unroll
    for (int mi = 0; mi < 4; ++mi)
        #pragma unroll
        for (int ni = 0; ni < 4; ++ni)
            #pragma unroll
            for (int rg = 0; rg < 4; ++rg)
                C[(size_t)(row0 + mi * 16 + rg) * N + (col0 + ni * 16)] =
                    acc[mi][ni][rg];
}

// ---------------------------------------------------------------------------
// Fused RMSNorm + RoPE + (optional) scale, in place, fp32.
// ---------------------------------------------------------------------------
__global__ __launch_bounds__(64) void norm_rope(float* __restrict__ t,
                                                const float* __restrict__ cosb,
                                                const float* __restrict__ sinb,
                                                const float* __restrict__ scale,
                                                int heads, float mulscale)
{
    const int lane = threadIdx.x;
    const int idx  = blockIdx.x;
    const int h    = idx % heads;
    const int m    = idx / heads;
    const int s    = m % S;

    float* row = t + (size_t)m * heads * HD + h * HD;
    float v = row[lane];

    float sq = v * v;
    #pragma unroll
    for (int off = 32; off; off >>= 1) sq += __shfl_xor(sq, off, 64);
    float inv = rsqrtf(sq * (1.0f / HD) + EPS);
    float n = v * inv * (1.0f + scale[lane]);

    float other = __shfl_xor(n, 32, 64);
    float rot   = (lane < 32) ? -other : other;
    float c  = cosb[(size_t)s * HD + lane];
    float sn = sinb[(size_t)s * HD + lane];
    row[lane] = (n * c + rot * sn) * mulscale;
}

// ---------------------------------------------------------------------------
// Flash attention v2: block = 4 waves = 256 thr covering 128 query rows.
// Wave = 32 queries x 2 lanes/query (lane&31 = query, lane>>5 = half-dim).
// Shared double-buffered K/V staging (global_load_lds). Fixed softmax max:
// RMSNorm => ||q_hat||<=1, ||k||<=8 => |score| <= 8 (Cauchy-Schwarz), so
// w = exp(score - 8): no running max, no rescale. Writes ctx as bf16.
// ---------------------------------------------------------------------------
__global__ __launch_bounds__(256, 4) void attn_flash(const float* __restrict__ qb,
                                                     const float* __restrict__ kb,
                                                     const float* __restrict__ vb,
                                                     unsigned short* __restrict__ ctx)
{
    constexpr int KT = 32;            // keys per tile
    __shared__ float Klds[2][KT * HD];   // 8 KB each
    __shared__ float Vlds[2][KT * HD];

    const int tid  = threadIdx.x;
    const int w    = tid >> 6;
    const int lane = tid & 63;
    const int qi   = lane & 31;
    const int half = lane >> 5;

    const int blk = blockIdx.x;
    const int qb4 = blk & 15;         // 16 row-blocks of 128 per (b,h)
    const int bh  = blk >> 4;
    const int h   = bh & (H - 1);
    const int b   = bh >> 5;
    const int g   = h >> 2;           // H/G = 4

    const int qp = qb4 * 128 + w * 32 + qi;
    const int nt = 4 * qb4 + 4;       // key tiles for the whole block
    const int tmax_w = 4 * qb4 + w;   // last tile this wave computes

    const float* kbase = kb + ((size_t)b * S * G + g) * HD;
    const float* vbase = vb + ((size_t)b * S * G + g) * HD;

    // q half-row -> registers (8 float4 = 32 dims)
    float4 qv[8];
    {
        const float4* qrow = (const float4*)(qb + ((size_t)(b * S + qp) * H + h) * HD + half * 32);
        #pragma unroll
        for (int i = 0; i < 8; ++i) qv[i] = qrow[i];
    }

    float4 acc[8];
    #pragma unroll
    for (int i = 0; i < 8; ++i) acc[i] = make_float4(0.f, 0.f, 0.f, 0.f);
    float l = 0.f;

    // cooperative stage of tile t into buffer buf: K+V, 4 loads/thread
    auto stage = [&](int t, int buf) {
        const int j0 = t * KT;
        #pragma unroll
        for (int i = 0; i < 2; ++i) {
            const int n   = i * 256 + tid;     // 16B chunk id, 0..511
            const int row = n >> 4;
            const int c4  = n & 15;
            const float* ks = kbase + (size_t)(j0 + row) * (G * HD) + c4 * 4;
            const float* vs = vbase + (size_t)(j0 + row) * (G * HD) + c4 * 4;
            const int cb = (i * 256 + w * 64) * 4;   // float index of wave's chunk base
            __builtin_amdgcn_global_load_lds((gas_u32*)ks, (las_u32*)&Klds[buf][cb], 16, 0, 0);
            __builtin_amdgcn_global_load_lds((gas_u32*)vs, (las_u32*)&Vlds[buf][cb], 16, 0, 0);
        }
    };

    stage(0, 0);

    for (int t = 0; t < nt; ++t) {
        const int cur = t & 1;
        if (t + 1 < nt) {
            stage(t + 1, cur ^ 1);
            asm volatile("s_waitcnt vmcnt(4)" ::: "memory");
        } else {
            asm volatile("s_waitcnt vmcnt(0)" ::: "memory");
        }
        __syncthreads();                      // tile t fully in LDS

        if (t <= tmax_w) {                    // wave-uniform causal skip
            const int j0 = t * KT;
            const float4* kt = (const float4*)&Klds[cur][0];
            const float4* vt = (const float4*)&Vlds[cur][0];
            #pragma unroll 4
            for (int j = 0; j < KT; ++j) {
                float s0 = 0.f, s1 = 0.f, s2 = 0.f, s3 = 0.f;
                #pragma unroll
                for (int d = 0; d < 8; ++d) {
                    float4 kv = kt[j * 16 + half * 8 + d];
                    s0 = fmaf(qv[d].x, kv.x, s0);
                    s1 = fmaf(qv[d].y, kv.y, s1);
                    s2 = fmaf(qv[d].z, kv.z, s2);
                    s3 = fmaf(qv[d].w, kv.w, s3);
                }
                float dot = (s0 + s1) + (s2 + s3);
                dot += __shfl_xor(dot, 32, 64);          // combine two halves
                const float wgt = (j0 + j <= qp) ? __expf(dot - 8.0f) : 0.f;
                l += wgt;
                #pragma unroll
                for (int d = 0; d < 8; ++d) {
                    float4 vv = vt[j * 16 + half * 8 + d];
                    acc[d].x = fmaf(wgt, vv.x, acc[d].x);
                    acc[d].y = fmaf(wgt, vv.y, acc[d].y);
                    acc[d].z = fmaf(wgt, vv.z, acc[d].z);
                    acc[d].w = fmaf(wgt, vv.w, acc[d].w);
                }
            }
        }
        __syncthreads();                      // everyone done with buf cur
    }

    const float inv = 1.f / l;
    unsigned short* crow = ctx + ((size_t)(b * S + qp) * H + h) * HD + half * 32;
    #pragma unroll
    for (int d = 0; d < 8; ++d) {
        ushort4 u;
        u.x = f2b(acc[d].x * inv);
        u.y = f2b(acc[d].y * inv);
        u.z = f2b(acc[d].z * inv);
        u.w = f2b(acc[d].w * inv);
        ((ushort4*)crow)[d] = u;
    }
}

// ---------------------------------------------------------------------------
extern "C" void kernel_launch(void* const* d_in, const int* in_sizes, int n_in,
                              void* d_out, int out_size, void* d_ws, size_t ws_size,
                              hipStream_t stream)
{
    const float* x       = (const float*)d_in[0];
    // d_in[1] = mask (bool) — ignored; causality computed structurally (k > q)
    const float* cosb    = (const float*)d_in[2];
    const float* sinb    = (const float*)d_in[3];
    const float* Wq      = (const float*)d_in[4];
    const float* Wk      = (const float*)d_in[5];
    const float* Wv      = (const float*)d_in[6];
    const float* Wo      = (const float*)d_in[7];
    const float* q_scale = (const float*)d_in[8];
    const float* k_scale = (const float*)d_in[9];
    float* out = (float*)d_out;

    // workspace layout (bf16 buffers first, then fp32) — ~71 MB total
    unsigned short* wsu = (unsigned short*)d_ws;
    size_t off = 0;
    unsigned short* x_bf   = wsu + off; off += (size_t)B * S * D;        // 8.39M
    unsigned short* Wq_bf  = wsu + off; off += (size_t)H * HD * D;       // 4.19M
    unsigned short* Wk_bf  = wsu + off; off += (size_t)G * HD * D;       // 1.05M
    unsigned short* Wv_bf  = wsu + off; off += (size_t)G * HD * D;       // 1.05M
    unsigned short* Wo_bf  = wsu + off; off += (size_t)D * H * HD;       // 4.19M
    unsigned short* ctx_bf = wsu + off; off += (size_t)B * S * H * HD;   // 8.39M
    float* kbuf = (float*)(wsu + off);
    float* vbuf = kbuf + (size_t)B * S * G * HD;
    float* qbuf = out;                 // q lives in d_out until final GEMM

    const int M = B * S;               // 4096

    // f32 -> bf16 conversions
    conv_f2b<<<512, 256, 0, stream>>>(x,  x_bf,  (B * S * D) / 4);
    conv_f2b<<<256, 256, 0, stream>>>(Wq, Wq_bf, (H * HD * D) / 4);
    conv_f2b<<<128, 256, 0, stream>>>(Wk, Wk_bf, (G * HD * D) / 4);
    conv_f2b<<<128, 256, 0, stream>>>(Wv, Wv_bf, (G * HD * D) / 4);
    conv_f2b<<<256, 256, 0, stream>>>(Wo, Wo_bf, (D * H * HD) / 4);

    // projections (bf16 MFMA, fp32 out)
    gemm_bf16<<<dim3((H * HD) / 128, M / 128), 256, 0, stream>>>(x_bf, Wq_bf, qbuf, M, H * HD, D);
    gemm_bf16<<<dim3((G * HD) / 128, M / 128), 256, 0, stream>>>(x_bf, Wk_bf, kbuf, M, G * HD, D);
    gemm_bf16<<<dim3((G * HD) / 128, M / 128), 256, 0, stream>>>(x_bf, Wv_bf, vbuf, M, G * HD, D);

    // RMSNorm + RoPE (+ q scaled by HD^-0.5)
    norm_rope<<<M * H, 64, 0, stream>>>(qbuf, cosb, sinb, q_scale, H, 0.125f);
    norm_rope<<<M * G, 64, 0, stream>>>(kbuf, cosb, sinb, k_scale, G, 1.0f);

    // attention -> ctx (bf16)
    attn_flash<<<16 * B * H, 256, 0, stream>>>(qbuf, kbuf, vbuf, ctx_bf);

    // out = ctx @ Wo^T
    gemm_bf16<<<dim3(D / 128, M / 128), 256, 0, stream>>>(ctx_bf, Wo_bf, out, M, D, D);
}

// Round 6
// 459.397 us; speedup vs baseline: 21.7900x; 3.4191x over previous
//
#include <hip/hip_runtime.h>
#include <hip/hip_bf16.h>
#include <stdint.h>

// Problem constants (match reference)
constexpr int B  = 2;
constexpr int S  = 2048;
constexpr int D  = 2048;
constexpr int H  = 32;
constexpr int G  = 8;
constexpr int HD = 64;
constexpr float EPS = 1e-6f;

constexpr float LOG2E  = 1.44269504088896341f;
constexpr float C8     = 8.0f * LOG2E;          // fixed softmax "max" in log2 units

typedef __attribute__((address_space(1))) const uint32_t  gas_u32;
typedef __attribute__((address_space(3))) uint32_t        las_u32;
typedef __attribute__((ext_vector_type(8))) short  bf16x8;   // 8 bf16 = 4 VGPR
typedef __attribute__((ext_vector_type(4))) float  f32x4;

static __device__ __forceinline__ unsigned short f2b(float f) {
    __hip_bfloat16 h = __float2bfloat16(f);
    return *reinterpret_cast<unsigned short*>(&h);
}

// ---------------------------------------------------------------------------
// f32 -> bf16 elementwise conversion (vectorized, grid-stride)
// ---------------------------------------------------------------------------
__global__ __launch_bounds__(256) void conv_f2b(const float* __restrict__ in,
                                                unsigned short* __restrict__ out,
                                                int n4)
{
    int i = blockIdx.x * blockDim.x + threadIdx.x;
    const int stride = gridDim.x * blockDim.x;
    for (; i < n4; i += stride) {
        float4 v = ((const float4*)in)[i];
        ushort4 o;
        o.x = f2b(v.x); o.y = f2b(v.y); o.z = f2b(v.z); o.w = f2b(v.w);
        ((ushort4*)out)[i] = o;
    }
}

// ---------------------------------------------------------------------------
// bf16 MFMA GEMM: C[M][N] = A[M][K] @ B[N][K]^T  (unchanged from round 5)
// ---------------------------------------------------------------------------
__global__ __launch_bounds__(256) void gemm_bf16(const unsigned short* __restrict__ A,
                                                 const unsigned short* __restrict__ Bm,
                                                 float* __restrict__ C,
                                                 int M, int N, int K)
{
    constexpr int BM = 128, BN = 128, BK = 64;
    __shared__ unsigned short As[BM * BK];
    __shared__ unsigned short Bs[BN * BK];

    const int tid  = threadIdx.x;
    const int w    = tid >> 6;
    const int lane = tid & 63;
    const int wr   = w >> 1, wc = w & 1;
    const int bm   = blockIdx.y * BM;
    const int bn   = blockIdx.x * BN;

    f32x4 acc[4][4];
    #pragma unroll
    for (int mi = 0; mi < 4; ++mi)
        #pragma unroll
        for (int ni = 0; ni < 4; ++ni)
            acc[mi][ni] = (f32x4){0.f, 0.f, 0.f, 0.f};

    for (int k0 = 0; k0 < K; k0 += BK) {
        #pragma unroll
        for (int i = 0; i < 4; ++i) {
            const int n  = i * 256 + tid;
            const int r  = n >> 3, cs = n & 7;
            const int cg = cs ^ (r & 7);
            const unsigned short* ga = A + (size_t)(bm + r) * K + k0 + cg * 8;
            __builtin_amdgcn_global_load_lds((gas_u32*)ga,
                (las_u32*)(As + (i * 256 + w * 64) * 8), 16, 0, 0);
        }
        #pragma unroll
        for (int i = 0; i < 4; ++i) {
            const int n  = i * 256 + tid;
            const int r  = n >> 3, cs = n & 7;
            const int cg = cs ^ (r & 7);
            const unsigned short* gb = Bm + (size_t)(bn + r) * K + k0 + cg * 8;
            __builtin_amdgcn_global_load_lds((gas_u32*)gb,
                (las_u32*)(Bs + (i * 256 + w * 64) * 8), 16, 0, 0);
        }
        asm volatile("s_waitcnt vmcnt(0)" ::: "memory");
        __syncthreads();

        #pragma unroll
        for (int ks = 0; ks < 2; ++ks) {
            bf16x8 af[4], bfr[4];
            #pragma unroll
            for (int mi = 0; mi < 4; ++mi) {
                const int r    = wr * 64 + mi * 16 + (lane & 15);
                const int c    = ks * 4 + (lane >> 4);
                const int slot = c ^ (r & 7);
                af[mi] = *(const bf16x8*)(As + r * 64 + slot * 8);
            }
            #pragma unroll
            for (int ni = 0; ni < 4; ++ni) {
                const int r    = wc * 64 + ni * 16 + (lane & 15);
                const int c    = ks * 4 + (lane >> 4);
                const int slot = c ^ (r & 7);
                bfr[ni] = *(const bf16x8*)(Bs + r * 64 + slot * 8);
            }
            #pragma unroll
            for (int mi = 0; mi < 4; ++mi)
                #pragma unroll
                for (int ni = 0; ni < 4; ++ni)
                    acc[mi][ni] = __builtin_amdgcn_mfma_f32_16x16x32_bf16(
                        af[mi], bfr[ni], acc[mi][ni], 0, 0, 0);
        }
        __syncthreads();
    }

    const int col0 = bn + wc * 64 + (lane & 15);
    const int row0 = bm + wr * 64 + (lane >> 4) * 4;
    #pragma unroll
    for (int mi = 0; mi < 4; ++mi)
        #pragma unroll
        for (int ni = 0; ni < 4; ++ni)
            #pragma unroll
            for (int rg = 0; rg < 4; ++rg)
                C[(size_t)(row0 + mi * 16 + rg) * N + (col0 + ni * 16)] =
                    acc[mi][ni][rg];
}

// ---------------------------------------------------------------------------
// Fused RMSNorm + RoPE + scale; f32 in, bf16 out (separate buffer).
// ---------------------------------------------------------------------------
__global__ __launch_bounds__(64) void norm_rope_bf(const float* __restrict__ t,
                                                   unsigned short* __restrict__ o,
                                                   const float* __restrict__ cosb,
                                                   const float* __restrict__ sinb,
                                                   const float* __restrict__ scale,
                                                   int heads, float mulscale)
{
    const int lane = threadIdx.x;
    const int idx  = blockIdx.x;
    const int h    = idx % heads;
    const int m    = idx / heads;
    const int s    = m % S;

    const float* row = t + ((size_t)m * heads + h) * HD;
    float v = row[lane];

    float sq = v * v;
    #pragma unroll
    for (int off = 32; off; off >>= 1) sq += __shfl_xor(sq, off, 64);
    float inv = rsqrtf(sq * (1.0f / HD) + EPS);
    float n = v * inv * (1.0f + scale[lane]);

    float other = __shfl_xor(n, 32, 64);
    float rot   = (lane < 32) ? -other : other;
    float c  = cosb[(size_t)s * HD + lane];
    float sn = sinb[(size_t)s * HD + lane];
    o[((size_t)m * heads + h) * HD + lane] = f2b((n * c + rot * sn) * mulscale);
}

// ---------------------------------------------------------------------------
// V transpose + bf16: v f32 [b][s][G][64] -> Vt bf16 [b][g][64][S]
// ---------------------------------------------------------------------------
__global__ __launch_bounds__(256) void vtrans(const float* __restrict__ v,
                                              unsigned short* __restrict__ vtb)
{
    __shared__ float tile[64][65];
    const int tid = threadIdx.x;
    const int blk = blockIdx.x;
    const int st  = blk & 31;
    const int g   = (blk >> 5) & 7;
    const int b   = blk >> 8;
    const int s0  = st * 64;

    {
        const int si = tid >> 2;
        const int fc = (tid & 3) * 16;
        const float* src = v + ((size_t)(b * S + s0 + si) * G + g) * HD + fc;
        #pragma unroll
        for (int u = 0; u < 4; ++u) {
            float4 a = ((const float4*)src)[u];
            tile[si][fc + u * 4 + 0] = a.x;
            tile[si][fc + u * 4 + 1] = a.y;
            tile[si][fc + u * 4 + 2] = a.z;
            tile[si][fc + u * 4 + 3] = a.w;
        }
    }
    __syncthreads();
    {
        const int d  = tid >> 2;
        const int sc = (tid & 3) * 16;
        ushort4 o[4];
        #pragma unroll
        for (int u = 0; u < 4; ++u) {
            o[u].x = f2b(tile[sc + u * 4 + 0][d]);
            o[u].y = f2b(tile[sc + u * 4 + 1][d]);
            o[u].z = f2b(tile[sc + u * 4 + 2][d]);
            o[u].w = f2b(tile[sc + u * 4 + 3][d]);
        }
        unsigned short* dst = vtb + ((size_t)(b * G + g) * HD + d) * S + s0 + sc;
        #pragma unroll
        for (int u = 0; u < 4; ++u)
            ((ushort4*)dst)[u] = o[u];
    }
}

// ---------------------------------------------------------------------------
// MFMA flash attention. 1 wave = 32 queries (2 groups of 16), KVBLK = 32.
// Swapped QK^T: sc = mfma(K_frag, Q_frag) -> C[key][query]. K rows stored in
// LDS in a permuted order so lane g4 = lane>>4 ends up holding P for keys
// 8*g4..8*g4+7 = exactly the A-fragment of the PV MFMA (no cross-lane).
// V staged from pre-transposed Vt with a chunk-XOR swizzle. Fixed softmax
// max (|score|<=8 by Cauchy-Schwarz after RMSNorm): w = exp2(s' - 8*log2e),
// q pre-scaled by 0.125*log2e. Mirror-paired q-blocks for load balance.
// ---------------------------------------------------------------------------
__global__ __launch_bounds__(64, 2) void attn_mfma(
    const unsigned short* __restrict__ qb,   // [B][S][H][64] bf16 (pre-scaled)
    const unsigned short* __restrict__ kb,   // [B][S][G][64] bf16
    const unsigned short* __restrict__ vtb,  // [B][G][64][S] bf16
    unsigned short* __restrict__ ctx)        // [B][S][H][64] bf16
{
    __shared__ unsigned short Kl[2][2048];   // 4 KB per buffer
    __shared__ unsigned short Vl[2][2048];   // V^T reshaped [32 dim-pairs][64]

    const int lane = threadIdx.x;
    const int g4   = lane >> 4;
    const int l15  = lane & 15;

    const int blk = blockIdx.x;
    const int pr  = blk & 31;           // pair index: q-blocks (pr, 63-pr)
    const int bh  = blk >> 5;
    const int h   = bh & 31;
    const int b   = bh >> 5;
    const int gg  = h >> 2;             // H/G = 4

    const unsigned short* kbase = kb  + ((size_t)b * S * G + gg) * HD;
    const unsigned short* vbase = vtb + (size_t)(b * G + gg) * HD * S;

    auto stageK = [&](int t, int buf) {
        #pragma unroll
        for (int ii = 0; ii < 4; ++ii) {
            const int n  = ii * 64 + lane;
            const int s  = n >> 3, c = n & 7;
            const int cp = c ^ (s & 7);                       // chunk swizzle
            const int key = ((s >> 2) & 3) * 8 + (s & 3) + ((s >> 4) << 2);
            const unsigned short* src = kbase + (size_t)(t * 32 + key) * (G * HD) + cp * 8;
            __builtin_amdgcn_global_load_lds((gas_u32*)src,
                (las_u32*)&Kl[buf][ii * 512], 16, 0, 0);
        }
    };
    auto stageV = [&](int t, int buf) {
        #pragma unroll
        for (int ii = 0; ii < 4; ++ii) {
            const int n  = ii * 64 + lane;
            const int d2 = n >> 3, c = n & 7;
            const int cp = c ^ (d2 & 7);
            const int d  = 2 * d2 + (cp >> 2);
            const unsigned short* src = vbase + (size_t)d * S + t * 32 + (cp & 3) * 8;
            __builtin_amdgcn_global_load_lds((gas_u32*)src,
                (las_u32*)&Vl[buf][ii * 512], 16, 0, 0);
        }
    };

    for (int pass = 0; pass < 2; ++pass) {
        const int qblk = pass ? (63 - pr) : pr;
        const int qb0  = qblk * 32;
        const int nt   = qblk + 1;

        // Q fragments: [qg][dc], lane&15 = query col, (lane>>4)*8 = d offset
        bf16x8 qf[2][2];
        #pragma unroll
        for (int qg = 0; qg < 2; ++qg)
            #pragma unroll
            for (int dc = 0; dc < 2; ++dc)
                qf[qg][dc] = *(const bf16x8*)(qb +
                    ((size_t)(b * S + qb0 + qg * 16 + l15) * H + h) * HD + dc * 32 + g4 * 8);

        f32x4 accO[2][4];
        #pragma unroll
        for (int qg = 0; qg < 2; ++qg)
            #pragma unroll
            for (int dg = 0; dg < 4; ++dg)
                accO[qg][dg] = (f32x4){0.f, 0.f, 0.f, 0.f};
        float lsum[2] = {0.f, 0.f};

        stageK(0, 0); stageV(0, 0);

        for (int t = 0; t < nt; ++t) {
            const int cur = t & 1;
            if (t + 1 < nt) {
                stageK(t + 1, cur ^ 1); stageV(t + 1, cur ^ 1);
                asm volatile("s_waitcnt vmcnt(8)" ::: "memory");
            } else {
                asm volatile("s_waitcnt vmcnt(0)" ::: "memory");
            }

            // ---- QK^T: sc[kg][qg] = C[key16][query16] ----
            f32x4 sc[2][2];
            #pragma unroll
            for (int kg = 0; kg < 2; ++kg)
                #pragma unroll
                for (int qg = 0; qg < 2; ++qg)
                    sc[kg][qg] = (f32x4){0.f, 0.f, 0.f, 0.f};
            #pragma unroll
            for (int kg = 0; kg < 2; ++kg) {
                const int srow = l15 + 16 * kg;
                #pragma unroll
                for (int dc = 0; dc < 2; ++dc) {
                    const int ch = (dc * 4 + g4) ^ (srow & 7);
                    bf16x8 kf = *(const bf16x8*)&Kl[cur][srow * 64 + ch * 8];
                    #pragma unroll
                    for (int qg = 0; qg < 2; ++qg)
                        sc[kg][qg] = __builtin_amdgcn_mfma_f32_16x16x32_bf16(
                            kf, qf[qg][dc], sc[kg][qg], 0, 0, 0);
                }
            }

            // ---- softmax weights (fixed max) + pack into PV A-fragment ----
            bf16x8 pf[2];
            #pragma unroll
            for (int qg = 0; qg < 2; ++qg) {
                const int qglob = qb0 + qg * 16 + l15;
                #pragma unroll
                for (int kg = 0; kg < 2; ++kg)
                    #pragma unroll
                    for (int r = 0; r < 4; ++r) {
                        const int kglob = t * 32 + g4 * 8 + kg * 4 + r;
                        float e = exp2f(sc[kg][qg][r] - C8);
                        e = (kglob <= qglob) ? e : 0.f;
                        lsum[qg] += e;
                        pf[qg][kg * 4 + r] = (short)f2b(e);
                    }
            }

            // ---- PV: accO[qg][dg] += P^T . V ----
            #pragma unroll
            for (int dg = 0; dg < 4; ++dg) {
                const int d2r = (l15 >> 1) + 8 * dg;
                const int ch  = (4 * (l15 & 1) + g4) ^ (d2r & 7);
                bf16x8 vf = *(const bf16x8*)&Vl[cur][d2r * 64 + ch * 8];
                #pragma unroll
                for (int qg = 0; qg < 2; ++qg)
                    accO[qg][dg] = __builtin_amdgcn_mfma_f32_16x16x32_bf16(
                        pf[qg], vf, accO[qg][dg], 0, 0, 0);
            }
        }

        // ---- finalize: reduce l across the 4-lane group, write ctx ----
        #pragma unroll
        for (int qg = 0; qg < 2; ++qg) {
            lsum[qg] += __shfl_xor(lsum[qg], 16, 64);
            lsum[qg] += __shfl_xor(lsum[qg], 32, 64);
        }
        #pragma unroll
        for (int qg = 0; qg < 2; ++qg)
            #pragma unroll
            for (int r = 0; r < 4; ++r) {
                const float linv = 1.f / __shfl(lsum[qg], g4 * 4 + r, 64);
                const int qrow = qb0 + qg * 16 + g4 * 4 + r;
                unsigned short* crow = ctx + ((size_t)(b * S + qrow) * H + h) * HD + l15;
                #pragma unroll
                for (int dg = 0; dg < 4; ++dg)
                    crow[dg * 16] = f2b(accO[qg][dg][r] * linv);
            }
    }
}

// ---------------------------------------------------------------------------
extern "C" void kernel_launch(void* const* d_in, const int* in_sizes, int n_in,
                              void* d_out, int out_size, void* d_ws, size_t ws_size,
                              hipStream_t stream)
{
    const float* x       = (const float*)d_in[0];
    // d_in[1] = mask (bool) — ignored; causality computed structurally (k > q)
    const float* cosb    = (const float*)d_in[2];
    const float* sinb    = (const float*)d_in[3];
    const float* Wq      = (const float*)d_in[4];
    const float* Wk      = (const float*)d_in[5];
    const float* Wv      = (const float*)d_in[6];
    const float* Wo      = (const float*)d_in[7];
    const float* q_scale = (const float*)d_in[8];
    const float* k_scale = (const float*)d_in[9];
    float* out = (float*)d_out;

    // workspace (shorts), ~71 MB total; aliases reuse dead buffers:
    unsigned short* wsu = (unsigned short*)d_ws;
    size_t off = 0;
    unsigned short* x_bf   = wsu + off; off += (size_t)B * S * D;        // 16.8 MB
    unsigned short* Wq_bf  = wsu + off; off += (size_t)H * HD * D;       //  8.4 MB
    unsigned short* Wk_bf  = wsu + off; off += (size_t)G * HD * D;       //  2.1 MB
    unsigned short* Wv_bf  = wsu + off; off += (size_t)G * HD * D;       //  2.1 MB
    unsigned short* Wo_bf  = wsu + off; off += (size_t)D * H * HD;       //  8.4 MB
    unsigned short* ctx_bf = wsu + off; off += (size_t)B * S * H * HD;   // 16.8 MB
    float* kbuf = (float*)(wsu + off);                                   //  8.4 MB
    float* vbuf = kbuf + (size_t)B * S * G * HD;                         //  8.4 MB
    float* qbuf = out;                        // q f32 lives in d_out until final GEMM
    unsigned short* q_bf = x_bf;              // x_bf dead after projection GEMMs
    unsigned short* k_bf = Wq_bf;             // Wq_bf dead after q GEMM
    unsigned short* Vt   = Wk_bf;             // Wk_bf+Wv_bf (4.2 MB) dead after k/v GEMMs

    const int M = B * S;                      // 4096

    // f32 -> bf16
    conv_f2b<<<512, 256, 0, stream>>>(x,  x_bf,  (B * S * D) / 4);
    conv_f2b<<<256, 256, 0, stream>>>(Wq, Wq_bf, (H * HD * D) / 4);
    conv_f2b<<<128, 256, 0, stream>>>(Wk, Wk_bf, (G * HD * D) / 4);
    conv_f2b<<<128, 256, 0, stream>>>(Wv, Wv_bf, (G * HD * D) / 4);
    conv_f2b<<<256, 256, 0, stream>>>(Wo, Wo_bf, (D * H * HD) / 4);

    // projections
    gemm_bf16<<<dim3((H * HD) / 128, M / 128), 256, 0, stream>>>(x_bf, Wq_bf, qbuf, M, H * HD, D);
    gemm_bf16<<<dim3((G * HD) / 128, M / 128), 256, 0, stream>>>(x_bf, Wk_bf, kbuf, M, G * HD, D);
    gemm_bf16<<<dim3((G * HD) / 128, M / 128), 256, 0, stream>>>(x_bf, Wv_bf, vbuf, M, G * HD, D);

    // RMSNorm + RoPE -> bf16 (q gets 1/8 * log2e folded in for exp2 softmax)
    norm_rope_bf<<<M * H, 64, 0, stream>>>(qbuf, q_bf, cosb, sinb, q_scale, H, 0.125f * LOG2E);
    norm_rope_bf<<<M * G, 64, 0, stream>>>(kbuf, k_bf, cosb, sinb, k_scale, G, 1.0f);

    // V -> transposed bf16 [b][g][64][S]
    vtrans<<<B * G * 32, 256, 0, stream>>>(vbuf, Vt);

    // MFMA flash attention -> ctx (bf16)
    attn_mfma<<<32 * B * H, 64, 0, stream>>>(q_bf, k_bf, Vt, ctx_bf);

    // out = ctx @ Wo^T
    gemm_bf16<<<dim3(D / 128, M / 128), 256, 0, stream>>>(ctx_bf, Wo_bf, out, M, D, D);
}

// Round 8
// 376.274 us; speedup vs baseline: 26.6036x; 1.2209x over previous
//
#include <hip/hip_runtime.h>
#include <hip/hip_bf16.h>
#include <stdint.h>
#include <type_traits>

// Problem constants (match reference)
constexpr int B  = 2;
constexpr int S  = 2048;
constexpr int D  = 2048;
constexpr int H  = 32;
constexpr int G  = 8;
constexpr int HD = 64;
constexpr float EPS = 1e-6f;

constexpr float LOG2E  = 1.44269504088896341f;
constexpr float C8     = 8.0f * LOG2E;          // fixed softmax "max" in log2 units

typedef __attribute__((address_space(1))) const uint32_t  gas_u32;
typedef __attribute__((address_space(3))) uint32_t        las_u32;
typedef __attribute__((ext_vector_type(8))) short  bf16x8;   // 8 bf16 = 4 VGPR
typedef __attribute__((ext_vector_type(4))) float  f32x4;

static __device__ __forceinline__ unsigned short f2b(float f) {
    __hip_bfloat16 h = __float2bfloat16(f);
    return *reinterpret_cast<unsigned short*>(&h);
}

// ---------------------------------------------------------------------------
// f32 -> bf16 elementwise conversion (vectorized, grid-stride)
// ---------------------------------------------------------------------------
__global__ __launch_bounds__(256) void conv_f2b(const float* __restrict__ in,
                                                unsigned short* __restrict__ out,
                                                int n4)
{
    int i = blockIdx.x * blockDim.x + threadIdx.x;
    const int stride = gridDim.x * blockDim.x;
    for (; i < n4; i += stride) {
        float4 v = ((const float4*)in)[i];
        ushort4 o;
        o.x = f2b(v.x); o.y = f2b(v.y); o.z = f2b(v.z); o.w = f2b(v.w);
        ((ushort4*)out)[i] = o;
    }
}

// ---------------------------------------------------------------------------
// Fused conversion of all four weight matrices into one contiguous bf16 blob
// (Wq | Wk | Wv | Wo). Segment boundaries in float4 units, compile-time.
// ---------------------------------------------------------------------------
__global__ __launch_bounds__(256) void conv_weights(const float* __restrict__ Wq,
                                                    const float* __restrict__ Wk,
                                                    const float* __restrict__ Wv,
                                                    const float* __restrict__ Wo,
                                                    unsigned short* __restrict__ out)
{
    constexpr int c1 = (H * HD * D) / 4;                 // 1048576
    constexpr int c2 = c1 + (G * HD * D) / 4;            // 1310720
    constexpr int c3 = c2 + (G * HD * D) / 4;            // 1572864
    constexpr int c4 = c3 + (D * H * HD) / 4;            // 2621440

    int i = blockIdx.x * blockDim.x + threadIdx.x;
    const int stride = gridDim.x * blockDim.x;
    for (; i < c4; i += stride) {
        float4 v;
        if      (i < c1) v = ((const float4*)Wq)[i];
        else if (i < c2) v = ((const float4*)Wk)[i - c1];
        else if (i < c3) v = ((const float4*)Wv)[i - c2];
        else             v = ((const float4*)Wo)[i - c3];
        ushort4 o;
        o.x = f2b(v.x); o.y = f2b(v.y); o.z = f2b(v.z); o.w = f2b(v.w);
        ((ushort4*)out)[i] = o;
    }
}

// ---------------------------------------------------------------------------
// bf16 MFMA GEMM: C[M][N] = A[M][K] @ B[N][K]^T  (unchanged, verified)
// ---------------------------------------------------------------------------
__global__ __launch_bounds__(256) void gemm_bf16(const unsigned short* __restrict__ A,
                                                 const unsigned short* __restrict__ Bm,
                                                 float* __restrict__ C,
                                                 int M, int N, int K)
{
    constexpr int BM = 128, BN = 128, BK = 64;
    __shared__ unsigned short As[BM * BK];
    __shared__ unsigned short Bs[BN * BK];

    const int tid  = threadIdx.x;
    const int w    = tid >> 6;
    const int lane = tid & 63;
    const int wr   = w >> 1, wc = w & 1;
    const int bm   = blockIdx.y * BM;
    const int bn   = blockIdx.x * BN;

    f32x4 acc[4][4];
    #pragma unroll
    for (int mi = 0; mi < 4; ++mi)
        #pragma unroll
        for (int ni = 0; ni < 4; ++ni)
            acc[mi][ni] = (f32x4){0.f, 0.f, 0.f, 0.f};

    for (int k0 = 0; k0 < K; k0 += BK) {
        #pragma unroll
        for (int i = 0; i < 4; ++i) {
            const int n  = i * 256 + tid;
            const int r  = n >> 3, cs = n & 7;
            const int cg = cs ^ (r & 7);
            const unsigned short* ga = A + (size_t)(bm + r) * K + k0 + cg * 8;
            __builtin_amdgcn_global_load_lds((gas_u32*)ga,
                (las_u32*)(As + (i * 256 + w * 64) * 8), 16, 0, 0);
        }
        #pragma unroll
        for (int i = 0; i < 4; ++i) {
            const int n  = i * 256 + tid;
            const int r  = n >> 3, cs = n & 7;
            const int cg = cs ^ (r & 7);
            const unsigned short* gb = Bm + (size_t)(bn + r) * K + k0 + cg * 8;
            __builtin_amdgcn_global_load_lds((gas_u32*)gb,
                (las_u32*)(Bs + (i * 256 + w * 64) * 8), 16, 0, 0);
        }
        asm volatile("s_waitcnt vmcnt(0)" ::: "memory");
        __syncthreads();

        #pragma unroll
        for (int ks = 0; ks < 2; ++ks) {
            bf16x8 af[4], bfr[4];
            #pragma unroll
            for (int mi = 0; mi < 4; ++mi) {
                const int r    = wr * 64 + mi * 16 + (lane & 15);
                const int c    = ks * 4 + (lane >> 4);
                const int slot = c ^ (r & 7);
                af[mi] = *(const bf16x8*)(As + r * 64 + slot * 8);
            }
            #pragma unroll
            for (int ni = 0; ni < 4; ++ni) {
                const int r    = wc * 64 + ni * 16 + (lane & 15);
                const int c    = ks * 4 + (lane >> 4);
                const int slot = c ^ (r & 7);
                bfr[ni] = *(const bf16x8*)(Bs + r * 64 + slot * 8);
            }
            #pragma unroll
            for (int mi = 0; mi < 4; ++mi)
                #pragma unroll
                for (int ni = 0; ni < 4; ++ni)
                    acc[mi][ni] = __builtin_amdgcn_mfma_f32_16x16x32_bf16(
                        af[mi], bfr[ni], acc[mi][ni], 0, 0, 0);
        }
        __syncthreads();
    }

    const int col0 = bn + wc * 64 + (lane & 15);
    const int row0 = bm + wr * 64 + (lane >> 4) * 4;
    #pragma unroll
    for (int mi = 0; mi < 4; ++mi)
        #pragma unroll
        for (int ni = 0; ni < 4; ++ni)
            #pragma unroll
            for (int rg = 0; rg < 4; ++rg)
                C[(size_t)(row0 + mi * 16 + rg) * N + (col0 + ni * 16)] =
                    acc[mi][ni][rg];
}

// ---------------------------------------------------------------------------
// Fused RMSNorm + RoPE for q AND k in one launch. 256-thr blocks, one wave
// per (row, head) unit. q units first (M*H), then k units (M*G).
// ---------------------------------------------------------------------------
__global__ __launch_bounds__(256) void norm_rope_fused(
    const float* __restrict__ qsrc,          // [M][2048] f32
    const float* __restrict__ kvsrc,         // [M][1024] f32 (k in cols 0..512)
    unsigned short* __restrict__ q_bf,       // [M][2048] bf16
    unsigned short* __restrict__ k_bf,       // [M][512]  bf16
    const float* __restrict__ cosb,
    const float* __restrict__ sinb,
    const float* __restrict__ q_scale,
    const float* __restrict__ k_scale)
{
    constexpr int NQ = B * S * H;            // 131072
    const int lane = threadIdx.x & 63;
    const int unit = blockIdx.x * 4 + (threadIdx.x >> 6);

    const float* src;
    unsigned short* dst;
    const float* scale;
    float mulscale;
    int m;
    if (unit < NQ) {
        m = unit >> 5;                       // /H
        const int h = unit & 31;
        src = qsrc + (size_t)m * 2048 + h * 64;
        dst = q_bf + (size_t)m * 2048 + h * 64;
        scale = q_scale; mulscale = 0.125f * LOG2E;
    } else {
        const int u2 = unit - NQ;
        m = u2 >> 3;                         // /G
        const int g = u2 & 7;
        src = kvsrc + (size_t)m * 1024 + g * 64;
        dst = k_bf + (size_t)m * 512 + g * 64;
        scale = k_scale; mulscale = 1.0f;
    }
    const int s = m & (S - 1);

    float v = src[lane];
    float sq = v * v;
    #pragma unroll
    for (int off = 32; off; off >>= 1) sq += __shfl_xor(sq, off, 64);
    float inv = rsqrtf(sq * (1.0f / HD) + EPS);
    float n = v * inv * (1.0f + scale[lane]);

    float other = __shfl_xor(n, 32, 64);
    float rot   = (lane < 32) ? -other : other;
    float c  = cosb[(size_t)s * HD + lane];
    float sn = sinb[(size_t)s * HD + lane];
    dst[lane] = f2b((n * c + rot * sn) * mulscale);
}

// ---------------------------------------------------------------------------
// V transpose + bf16: kv f32 [b][s][1024] (v at col 512+g*64) -> Vt bf16
// [b][g][64][S]
// ---------------------------------------------------------------------------
__global__ __launch_bounds__(256) void vtrans(const float* __restrict__ kv,
                                              unsigned short* __restrict__ vtb)
{
    __shared__ float tile[64][65];
    const int tid = threadIdx.x;
    const int blk = blockIdx.x;
    const int st  = blk & 31;
    const int g   = (blk >> 5) & 7;
    const int b   = blk >> 8;
    const int s0  = st * 64;

    {
        const int si = tid >> 2;
        const int fc = (tid & 3) * 16;
        const float* src = kv + (size_t)(b * S + s0 + si) * 1024 + 512 + g * 64 + fc;
        #pragma unroll
        for (int u = 0; u < 4; ++u) {
            float4 a = ((const float4*)src)[u];
            tile[si][fc + u * 4 + 0] = a.x;
            tile[si][fc + u * 4 + 1] = a.y;
            tile[si][fc + u * 4 + 2] = a.z;
            tile[si][fc + u * 4 + 3] = a.w;
        }
    }
    __syncthreads();
    {
        const int d  = tid >> 2;
        const int sc = (tid & 3) * 16;
        ushort4 o[4];
        #pragma unroll
        for (int u = 0; u < 4; ++u) {
            o[u].x = f2b(tile[sc + u * 4 + 0][d]);
            o[u].y = f2b(tile[sc + u * 4 + 1][d]);
            o[u].z = f2b(tile[sc + u * 4 + 2][d]);
            o[u].w = f2b(tile[sc + u * 4 + 3][d]);
        }
        unsigned short* dst = vtb + ((size_t)(b * G + g) * HD + d) * S + s0 + sc;
        #pragma unroll
        for (int u = 0; u < 4; ++u)
            ((ushort4*)dst)[u] = o[u];
    }
}

// ---------------------------------------------------------------------------
// MFMA flash attention v2: block = 4 waves, wave w owns q-block 4j+w (32
// queries) of one (b,h); K/V tiles staged cooperatively (each wave 1 K + 1 V
// chunk), double-buffered; one __syncthreads per tile (its implicit
// vmcnt-drain is the fence for the PREVIOUS stage, issued one tile earlier).
// Long blocks (high j) scheduled first via reversed j index.
// ---------------------------------------------------------------------------
__global__ __launch_bounds__(256, 4) void attn_mfma(
    const unsigned short* __restrict__ qb,   // [B][S][H][64] bf16 (pre-scaled)
    const unsigned short* __restrict__ kb,   // [B][S][G][64] bf16
    const unsigned short* __restrict__ vtb,  // [B][G][64][S] bf16
    unsigned short* __restrict__ ctx)        // [B][S][H][64] bf16
{
    __shared__ unsigned short Kl[2][2048];   // 4 KB per buffer
    __shared__ unsigned short Vl[2][2048];

    const int tid  = threadIdx.x;
    const int w    = tid >> 6;
    const int lane = tid & 63;
    const int g4   = lane >> 4;
    const int l15  = lane & 15;

    const int blk  = blockIdx.x;
    const int bh   = blk & 63;
    const int j    = 15 - (blk >> 6);       // long blocks first
    const int h    = bh & 31;
    const int b    = bh >> 5;
    const int gg   = h >> 2;                // H/G = 4

    const int qblk  = 4 * j + w;            // this wave's q-block
    const int qb0   = qblk * 32;
    const int ntmax = 4 * j + 4;            // tiles staged by the block

    const unsigned short* kbase = kb  + ((size_t)b * S * G + gg) * HD;
    const unsigned short* vbase = vtb + (size_t)(b * G + gg) * HD * S;

    // wave w stages its K chunk and V chunk of tile t into buffer buf
    auto stageK = [&](int t, int buf) {
        const int n  = w * 64 + lane;
        const int s  = n >> 3, c = n & 7;
        const int cp = c ^ (s & 7);                       // chunk swizzle
        const int key = ((s >> 2) & 3) * 8 + (s & 3) + ((s >> 4) << 2);
        const unsigned short* src = kbase + (size_t)(t * 32 + key) * (G * HD) + cp * 8;
        __builtin_amdgcn_global_load_lds((gas_u32*)src,
            (las_u32*)&Kl[buf][w * 512], 16, 0, 0);
    };
    auto stageV = [&](int t, int buf) {
        const int n  = w * 64 + lane;
        const int d2 = n >> 3, c = n & 7;
        const int cp = c ^ (d2 & 7);
        const int d  = 2 * d2 + (cp >> 2);
        const unsigned short* src = vbase + (size_t)d * S + t * 32 + (cp & 3) * 8;
        __builtin_amdgcn_global_load_lds((gas_u32*)src,
            (las_u32*)&Vl[buf][w * 512], 16, 0, 0);
    };

    // Q fragments: [qg][dc], lane&15 = query col, (lane>>4)*8 = d offset
    bf16x8 qf[2][2];
    #pragma unroll
    for (int qg = 0; qg < 2; ++qg)
        #pragma unroll
        for (int dc = 0; dc < 2; ++dc)
            qf[qg][dc] = *(const bf16x8*)(qb +
                ((size_t)(b * S + qb0 + qg * 16 + l15) * H + h) * HD + dc * 32 + g4 * 8);

    f32x4 accO[2][4];
    #pragma unroll
    for (int qg = 0; qg < 2; ++qg)
        #pragma unroll
        for (int dg = 0; dg < 4; ++dg)
            accO[qg][dg] = (f32x4){0.f, 0.f, 0.f, 0.f};
    float lsum[2] = {0.f, 0.f};

    // tile compute; DIAG selects causal masking (diagonal tile only)
    auto tile_body = [&](int t, int cur, auto DIAG) {
        constexpr bool diag = decltype(DIAG)::value;

        // ---- QK^T: sc[kg][qg] = C[key16][query16] ----
        f32x4 sc[2][2];
        #pragma unroll
        for (int kg = 0; kg < 2; ++kg)
            #pragma unroll
            for (int qg = 0; qg < 2; ++qg)
                sc[kg][qg] = (f32x4){0.f, 0.f, 0.f, 0.f};
        __builtin_amdgcn_s_setprio(1);
        #pragma unroll
        for (int kg = 0; kg < 2; ++kg) {
            const int srow = l15 + 16 * kg;
            #pragma unroll
            for (int dc = 0; dc < 2; ++dc) {
                const int ch = (dc * 4 + g4) ^ (srow & 7);
                bf16x8 kf = *(const bf16x8*)&Kl[cur][srow * 64 + ch * 8];
                #pragma unroll
                for (int qg = 0; qg < 2; ++qg)
                    sc[kg][qg] = __builtin_amdgcn_mfma_f32_16x16x32_bf16(
                        kf, qf[qg][dc], sc[kg][qg], 0, 0, 0);
            }
        }
        __builtin_amdgcn_s_setprio(0);

        // ---- softmax weights (fixed max) packed into PV A-fragment ----
        bf16x8 pf[2];
        #pragma unroll
        for (int qg = 0; qg < 2; ++qg) {
            const int qglob = qb0 + qg * 16 + l15;
            #pragma unroll
            for (int kg = 0; kg < 2; ++kg)
                #pragma unroll
                for (int r = 0; r < 4; ++r) {
                    float e = exp2f(sc[kg][qg][r] - C8);
                    if constexpr (diag) {
                        const int kglob = t * 32 + g4 * 8 + kg * 4 + r;
                        e = (kglob <= qglob) ? e : 0.f;
                    }
                    lsum[qg] += e;
                    pf[qg][kg * 4 + r] = (short)f2b(e);
                }
        }

        // ---- PV: accO[qg][dg] += P^T . V ----
        __builtin_amdgcn_s_setprio(1);
        #pragma unroll
        for (int dg = 0; dg < 4; ++dg) {
            const int d2r = (l15 >> 1) + 8 * dg;
            const int ch  = (4 * (l15 & 1) + g4) ^ (d2r & 7);
            bf16x8 vf = *(const bf16x8*)&Vl[cur][d2r * 64 + ch * 8];
            #pragma unroll
            for (int qg = 0; qg < 2; ++qg)
                accO[qg][dg] = __builtin_amdgcn_mfma_f32_16x16x32_bf16(
                    pf[qg], vf, accO[qg][dg], 0, 0, 0);
        }
        __builtin_amdgcn_s_setprio(0);
    };

    stageK(0, 0); stageV(0, 0);

    for (int t = 0; t < ntmax; ++t) {
        const int cur = t & 1;
        __syncthreads();                     // drains own vmcnt; tile t ready
        if (t + 1 < ntmax) { stageK(t + 1, cur ^ 1); stageV(t + 1, cur ^ 1); }
        if (t < qblk)       tile_body(t, cur, std::false_type{});
        else if (t == qblk) tile_body(t, cur, std::true_type{});
    }

    // ---- finalize: reduce l across the 4-lane group, write ctx ----
    #pragma unroll
    for (int qg = 0; qg < 2; ++qg) {
        lsum[qg] += __shfl_xor(lsum[qg], 16, 64);
        lsum[qg] += __shfl_xor(lsum[qg], 32, 64);
    }
    #pragma unroll
    for (int qg = 0; qg < 2; ++qg)
        #pragma unroll
        for (int r = 0; r < 4; ++r) {
            const float linv = 1.f / __shfl(lsum[qg], g4 * 4 + r, 64);
            const int qrow = qb0 + qg * 16 + g4 * 4 + r;
            unsigned short* crow = ctx + ((size_t)(b * S + qrow) * H + h) * HD + l15;
            #pragma unroll
            for (int dg = 0; dg < 4; ++dg)
                crow[dg * 16] = f2b(accO[qg][dg][r] * linv);
        }
}

// ---------------------------------------------------------------------------
extern "C" void kernel_launch(void* const* d_in, const int* in_sizes, int n_in,
                              void* d_out, int out_size, void* d_ws, size_t ws_size,
                              hipStream_t stream)
{
    const float* x       = (const float*)d_in[0];
    // d_in[1] = mask (bool) — ignored; causality computed structurally (k > q)
    const float* cosb    = (const float*)d_in[2];
    const float* sinb    = (const float*)d_in[3];
    const float* Wq      = (const float*)d_in[4];
    const float* Wk      = (const float*)d_in[5];
    const float* Wv      = (const float*)d_in[6];
    const float* Wo      = (const float*)d_in[7];
    const float* q_scale = (const float*)d_in[8];
    const float* k_scale = (const float*)d_in[9];
    float* out = (float*)d_out;

    // workspace (shorts), ~71 MB total; aliases reuse dead buffers
    unsigned short* wsu = (unsigned short*)d_ws;
    size_t off = 0;
    unsigned short* x_bf   = wsu + off; off += (size_t)B * S * D;        // 16.8 MB
    unsigned short* Wq_bf  = wsu + off; off += (size_t)H * HD * D;       //  8.4 MB
    unsigned short* Wk_bf  = wsu + off; off += (size_t)G * HD * D;       //  2.1 MB
    unsigned short* Wv_bf  = wsu + off; off += (size_t)G * HD * D;       //  2.1 MB
    unsigned short* Wo_bf  = wsu + off; off += (size_t)D * H * HD;       //  8.4 MB
    unsigned short* ctx_bf = wsu + off; off += (size_t)B * S * H * HD;   // 16.8 MB
    float* kvbuf = (float*)(wsu + off);       // [M][1024] f32, 16.8 MB
    float* qbuf = out;                        // q f32 lives in d_out until final GEMM
    unsigned short* q_bf = x_bf;              // x_bf dead after projection GEMMs
    unsigned short* k_bf = Wq_bf;             // Wq_bf dead after q GEMM
    unsigned short* Vt   = Wk_bf;             // Wk_bf+Wv_bf dead after kv GEMM

    const int M = B * S;                      // 4096

    // f32 -> bf16 (x + all four weights in two launches)
    conv_f2b<<<512, 256, 0, stream>>>(x, x_bf, (B * S * D) / 4);
    conv_weights<<<512, 256, 0, stream>>>(Wq, Wk, Wv, Wo, Wq_bf);

    // projections: q (N=2048) and fused k|v (N=1024; Wk_bf,Wv_bf contiguous)
    gemm_bf16<<<dim3(2048 / 128, M / 128), 256, 0, stream>>>(x_bf, Wq_bf, qbuf, M, 2048, D);
    gemm_bf16<<<dim3(1024 / 128, M / 128), 256, 0, stream>>>(x_bf, Wk_bf, kvbuf, M, 1024, D);

    // fused RMSNorm + RoPE for q and k -> bf16 (q gets 0.125*log2e folded in)
    norm_rope_fused<<<(M * (H + G)) / 4, 256, 0, stream>>>(
        qbuf, kvbuf, q_bf, k_bf, cosb, sinb, q_scale, k_scale);

    // V -> transposed bf16 [b][g][64][S]
    vtrans<<<B * G * 32, 256, 0, stream>>>(kvbuf, Vt);

    // MFMA flash attention -> ctx (bf16)
    attn_mfma<<<16 * B * H / 4 * 4, 256, 0, stream>>>(q_bf, k_bf, Vt, ctx_bf);

    // out = ctx @ Wo^T
    gemm_bf16<<<dim3(D / 128, M / 128), 256, 0, stream>>>(ctx_bf, Wo_bf, out, M, D, D);
}